// Round 7
// baseline (655.669 us; speedup 1.0000x reference)
//
#include <hip/hip_runtime.h>
#include <hip/hip_bf16.h>

#define ND 128
#define LDO 512
#define ALPHA 0.2f
#define L2EPS 1e-12f
#define SCAN_B 256
#define NCHUNK 256     // edge chunks for bucket hist/scatter
#define RPB 512        // rows per bucket (shift 9)

typedef __attribute__((ext_vector_type(8))) short short8;
typedef __attribute__((ext_vector_type(4))) float f32x4;

__device__ __forceinline__ short f2bf(float f) {
    union { float f; unsigned u; } c; c.f = f;
    unsigned u = c.u;
    unsigned r = (u + 0x7fffu + ((u >> 16) & 1u)) >> 16;   // RNE
    return (short)r;
}
__device__ __forceinline__ float bf2f(unsigned short u) {
    union { unsigned u; float f; } c; c.u = ((unsigned)u) << 16;
    return c.f;
}
__device__ __forceinline__ void gload_lds16(const void* g, void* l) {
    __builtin_amdgcn_global_load_lds(
        (const __attribute__((address_space(1))) unsigned int*)g,
        (__attribute__((address_space(3))) unsigned int*)l, 16, 0, 0);
}

// ---------------- copy embeddings into out[:, 0:128] and xb0 ----------------
__global__ void copy_emb_kernel(const float* __restrict__ emb, float* __restrict__ out,
                                unsigned short* __restrict__ xb, int n) {
    int idx = blockIdx.x * blockDim.x + threadIdx.x;
    int total = n * 32;
    if (idx >= total) return;
    int r = idx >> 5, c4 = idx & 31;
    const float4 v = *reinterpret_cast<const float4*>(emb + (size_t)r * ND + c4 * 4);
    *reinterpret_cast<float4*>(out + (size_t)r * LDO + c4 * 4) = v;
    ushort4 b;
    b.x = (unsigned short)f2bf(v.x); b.y = (unsigned short)f2bf(v.y);
    b.z = (unsigned short)f2bf(v.z); b.w = (unsigned short)f2bf(v.w);
    *reinterpret_cast<ushort4*>(xb + (size_t)r * ND + c4 * 4) = b;
}

// ---------------- pass A: per-chunk bucket histogram (LDS only) ----------------
__global__ __launch_bounds__(256) void bucket_hist_kernel(const int* __restrict__ erow,
                                                          int* __restrict__ gcnt,
                                                          int n_edges, int nb, int ch) {
    __shared__ int cnt[256];
    int b = blockIdx.x;
    cnt[threadIdx.x] = 0;
    __syncthreads();
    int s = b * ch, e = min(n_edges, s + ch);
    for (int j = s + threadIdx.x; j < e; j += 256) {
        atomicAdd(&cnt[erow[j] >> 9], 1);
    }
    __syncthreads();
    for (int i = threadIdx.x; i < nb; i += 256) gcnt[i * NCHUNK + b] = cnt[i];
}

// ---------------- scans ----------------
__global__ __launch_bounds__(SCAN_B) void scanA_kernel(const int* __restrict__ in,
                                                       int* __restrict__ outp,
                                                       int* __restrict__ partials, int n) {
    __shared__ int sm[SCAN_B];
    int i = blockIdx.x * SCAN_B + threadIdx.x;
    int v = (i < n) ? in[i] : 0;
    sm[threadIdx.x] = v;
    __syncthreads();
#pragma unroll
    for (int off = 1; off < SCAN_B; off <<= 1) {
        int t = (threadIdx.x >= off) ? sm[threadIdx.x - off] : 0;
        __syncthreads();
        sm[threadIdx.x] += t;
        __syncthreads();
    }
    if (i < n) outp[i] = sm[threadIdx.x] - v;
    if (threadIdx.x == SCAN_B - 1) partials[blockIdx.x] = sm[SCAN_B - 1];
}

__global__ __launch_bounds__(512) void scanB_kernel(int* __restrict__ partials, int nb) {
    __shared__ int sm[512];
    int v = (threadIdx.x < nb) ? partials[threadIdx.x] : 0;
    sm[threadIdx.x] = v;
    __syncthreads();
#pragma unroll
    for (int off = 1; off < 512; off <<= 1) {
        int t = (threadIdx.x >= off) ? sm[threadIdx.x - off] : 0;
        __syncthreads();
        sm[threadIdx.x] += t;
        __syncthreads();
    }
    if (threadIdx.x < nb) partials[threadIdx.x] = sm[threadIdx.x] - v;
}

__global__ void scan_add_kernel(int* __restrict__ arr, const int* __restrict__ partials, int n) {
    int i = blockIdx.x * blockDim.x + threadIdx.x;
    if (i < n) arr[i] += partials[i >> 8];
}

// ---------------- pass B: scatter into bucket-grouped tmp (coalesced runs) ----------------
__global__ __launch_bounds__(256) void bucket_scatter_kernel(const int* __restrict__ erow,
                                                             const int* __restrict__ ecol,
                                                             const float* __restrict__ eval,
                                                             const int* __restrict__ gbase,
                                                             int2* __restrict__ tmp,
                                                             int n_edges, int nb, int ch) {
    __shared__ int cur[256];
    int b = blockIdx.x;
    for (int i = threadIdx.x; i < nb; i += 256) cur[i] = gbase[i * NCHUNK + b];
    __syncthreads();
    int s = b * ch, e = min(n_edges, s + ch);
    for (int j = s + threadIdx.x; j < e; j += 256) {
        int r = erow[j];
        int pos = atomicAdd(&cur[r >> 9], 1);
        int2 p;
        p.x = ecol[j] | ((r & (RPB - 1)) << 17);     // col (17b) | row-low (9b)
        p.y = __float_as_int(eval[j]);
        tmp[pos] = p;
    }
}

// ---------------- pass C: per-bucket counting sort into final CSR pv + row_start ----------
__global__ __launch_bounds__(256) void bucket_sort_kernel(const int2* __restrict__ tmp,
                                                          const int* __restrict__ gbase,
                                                          int2* __restrict__ pv,
                                                          int* __restrict__ row_start,
                                                          int n, int n_edges, int nb) {
    __shared__ int hist[RPB];
    __shared__ int cur[RPB];
    __shared__ int sc[256];
    const int t = threadIdx.x;
    const int bkt = blockIdx.x;
    const int r0 = bkt << 9;
    const int s = gbase[bkt * NCHUNK];
    const int e = (bkt + 1 < nb) ? gbase[(bkt + 1) * NCHUNK] : n_edges;

    for (int i = t; i < RPB; i += 256) hist[i] = 0;
    __syncthreads();
    for (int j = s + t; j < e; j += 256) atomicAdd(&hist[tmp[j].x >> 17], 1);
    __syncthreads();
    int a0 = hist[2 * t], a1 = hist[2 * t + 1];
    sc[t] = a0 + a1;
    __syncthreads();
#pragma unroll
    for (int off = 1; off < 256; off <<= 1) {
        int v = (t >= off) ? sc[t - off] : 0;
        __syncthreads();
        sc[t] += v;
        __syncthreads();
    }
    int base = s + sc[t] - a0 - a1;
    cur[2 * t] = base;
    cur[2 * t + 1] = base + a0;
    __syncthreads();
    int r1 = min(n, r0 + RPB);
    for (int i = t; i < r1 - r0; i += 256) row_start[r0 + i] = cur[i];
    if (t == 0 && r1 == n) row_start[n] = n_edges;
    __syncthreads();
    for (int j = s + t; j < e; j += 256) {
        int2 p = tmp[j];
        int pos = atomicAdd(&cur[p.x >> 17], 1);
        int2 q;
        q.x = p.x & 0x1FFFF;
        q.y = p.y;
        pv[pos] = q;
    }
}

// ---------------- prep: Wt2[layer][h][nr][..] pre-swizzled bf16, bsum = bgc+bbi ----------
__global__ void prep_w_kernel(const float* __restrict__ Wgc, const float* __restrict__ bgc,
                              const float* __restrict__ Wbi, const float* __restrict__ bbi,
                              short* __restrict__ Wt2, float* __restrict__ bsum) {
    int z = blockIdx.x;
    int k = blockIdx.y;            // K index within half, 0..127
    int t = threadIdx.x;
    int nn = t & 127;              // N index
    int h  = (t < 128) ? 0 : 1;    // half 0 = Wgc (prop), 1 = Wbi (xm)
    const float* src = h ? (Wbi + ((size_t)z * 128 + k) * 128)
                         : (Wgc + ((size_t)z * 128 + k) * 128);
    float v = src[nn];
    int idx16 = k >> 3, e8 = k & 7;
    size_t addr = ((size_t)(z * 2 + h) * 128 + nn) * 128 + ((idx16 ^ (nn & 7)) << 3) + e8;
    Wt2[addr] = f2bf(v);
    if (k == 0 && t < 128) bsum[z * 128 + t] = bgc[z * 128 + t] + bbi[z * 128 + t];
}

// ---------------- merged layer: edge-gather SPMM -> LDS -> MFMA -> epilogue --------------
// block = 256 thr (4 waves), 64 rows. Reads xb_in (prev x, bf16), writes fp32 out slice +
// xb_out (next x, bf16). xb double-buffered across layers (gather reads race otherwise).
__global__ __launch_bounds__(256) void fused_spmm_layer(
        const int* __restrict__ row_start,
        const int2* __restrict__ pv,
        const unsigned short* __restrict__ xb_in,   // [n][128] bf16
        const short* __restrict__ Wt2,              // [2][128][128] pre-swizzled (layer base)
        const float* __restrict__ bsum,             // [128]
        float* __restrict__ xout,                   // row stride LDO (fp32 out slice)
        unsigned short* __restrict__ xb_out,        // [n][128] bf16
        int n) {
    __shared__ short A_lds[64 * 256];    // 32 KB
    __shared__ short W_lds[128 * 128];   // 32 KB

    const int tid  = threadIdx.x;
    const int row0 = blockIdx.x * 64;
    const int lane = tid & 63;
    const int w    = tid >> 6;
    const int lrow = lane & 15;
    const int kgrp = lane >> 4;

    // ---- issue W half-0 async (hides under gather) ----
    {
        const char* gW = (const char*)Wt2 + w * 8192 + lane * 16;
        char*       lW = (char*)W_lds + w * 8192;
#pragma unroll
        for (int it = 0; it < 8; ++it) gload_lds16(gW + it * 1024, lW + it * 1024);
    }

    // ---- gather phase: half-wave hw handles 8 rows, fp32 accumulate, write pr/xm to A_lds ----
    {
        const int hw = tid >> 5;          // 0..7
        const int l  = tid & 31;
        const int ck = l >> 1, lo = (l & 1) * 4;
        for (int rr = 0; rr < 8; ++rr) {
            int r_loc = hw * 8 + rr;      // 0..63
            int r = row0 + r_loc;
            int sz = r_loc & 7;
            unsigned short* ap = (unsigned short*)A_lds + r_loc * 256;
            if (r < n) {
                int s = row_start[r], e = row_start[r + 1];
                float a0 = 0.f, a1 = 0.f, a2 = 0.f, a3 = 0.f;
                int j = s;
                for (; j + 3 < e; j += 4) {
                    int2 p0 = pv[j], p1 = pv[j + 1], p2 = pv[j + 2], p3 = pv[j + 3];
                    float v0 = __int_as_float(p0.y), v1 = __int_as_float(p1.y);
                    float v2 = __int_as_float(p2.y), v3 = __int_as_float(p3.y);
                    ushort4 x0 = *reinterpret_cast<const ushort4*>(xb_in + (size_t)p0.x * ND + l * 4);
                    ushort4 x1 = *reinterpret_cast<const ushort4*>(xb_in + (size_t)p1.x * ND + l * 4);
                    ushort4 x2 = *reinterpret_cast<const ushort4*>(xb_in + (size_t)p2.x * ND + l * 4);
                    ushort4 x3 = *reinterpret_cast<const ushort4*>(xb_in + (size_t)p3.x * ND + l * 4);
                    a0 += v0 * bf2f(x0.x) + v1 * bf2f(x1.x) + v2 * bf2f(x2.x) + v3 * bf2f(x3.x);
                    a1 += v0 * bf2f(x0.y) + v1 * bf2f(x1.y) + v2 * bf2f(x2.y) + v3 * bf2f(x3.y);
                    a2 += v0 * bf2f(x0.z) + v1 * bf2f(x1.z) + v2 * bf2f(x2.z) + v3 * bf2f(x3.z);
                    a3 += v0 * bf2f(x0.w) + v1 * bf2f(x1.w) + v2 * bf2f(x2.w) + v3 * bf2f(x3.w);
                }
                for (; j < e; ++j) {
                    int2 p0 = pv[j];
                    float v0 = __int_as_float(p0.y);
                    ushort4 x0 = *reinterpret_cast<const ushort4*>(xb_in + (size_t)p0.x * ND + l * 4);
                    a0 += v0 * bf2f(x0.x);
                    a1 += v0 * bf2f(x0.y);
                    a2 += v0 * bf2f(x0.z);
                    a3 += v0 * bf2f(x0.w);
                }
                ushort4 xv = *reinterpret_cast<const ushort4*>(xb_in + (size_t)r * ND + l * 4);
                float x0 = bf2f(xv.x), x1 = bf2f(xv.y), x2 = bf2f(xv.z), x3 = bf2f(xv.w);
                ushort4 prv, xmv;
                prv.x = (unsigned short)f2bf(x0 + a0); prv.y = (unsigned short)f2bf(x1 + a1);
                prv.z = (unsigned short)f2bf(x2 + a2); prv.w = (unsigned short)f2bf(x3 + a3);
                xmv.x = (unsigned short)f2bf(x0 * a0); xmv.y = (unsigned short)f2bf(x1 * a1);
                xmv.z = (unsigned short)f2bf(x2 * a2); xmv.w = (unsigned short)f2bf(x3 * a3);
                *reinterpret_cast<ushort4*>(ap + (((ck)      ^ sz) << 3) + lo) = prv;
                *reinterpret_cast<ushort4*>(ap + (((16 + ck) ^ sz) << 3) + lo) = xmv;
            } else {
                ushort4 z; z.x = z.y = z.z = z.w = 0;
                *reinterpret_cast<ushort4*>(ap + (((ck)      ^ sz) << 3) + lo) = z;
                *reinterpret_cast<ushort4*>(ap + (((16 + ck) ^ sz) << 3) + lo) = z;
            }
        }
    }
    asm volatile("s_waitcnt vmcnt(0)" ::: "memory");
    __syncthreads();

    f32x4 acc[8];
#pragma unroll
    for (int nf = 0; nf < 8; ++nf) acc[nf] = (f32x4){0.f, 0.f, 0.f, 0.f};

    const int ar  = w * 16 + lrow;
    const int as_ = ar & 7;

    // ---- half 0 (prop @ Wgc) ----
#pragma unroll
    for (int ksl = 0; ksl < 4; ++ksl) {
        int kkl = ksl * 4 + kgrp;                    // 0..15
        short8 af = *reinterpret_cast<const short8*>(&A_lds[ar * 256 + ((kkl ^ as_) << 3)]);
#pragma unroll
        for (int nf = 0; nf < 8; ++nf) {
            int nr = nf * 16 + lrow;
            short8 bfr = *reinterpret_cast<const short8*>(&W_lds[nr * 128 + ((kkl ^ (nr & 7)) << 3)]);
            acc[nf] = __builtin_amdgcn_mfma_f32_16x16x32_bf16(af, bfr, acc[nf], 0, 0, 0);
        }
    }
    __syncthreads();
    // ---- stage W half 1 ----
    {
        const char* gW = (const char*)Wt2 + 32768 + w * 8192 + lane * 16;
        char*       lW = (char*)W_lds + w * 8192;
#pragma unroll
        for (int it = 0; it < 8; ++it) gload_lds16(gW + it * 1024, lW + it * 1024);
    }
    asm volatile("s_waitcnt vmcnt(0)" ::: "memory");
    __syncthreads();

    // ---- half 1 (xm @ Wbi) ----
#pragma unroll
    for (int ksl = 0; ksl < 4; ++ksl) {
        int kkl = ksl * 4 + kgrp;
        short8 af = *reinterpret_cast<const short8*>(&A_lds[ar * 256 + (((16 + kkl) ^ as_) << 3)]);
#pragma unroll
        for (int nf = 0; nf < 8; ++nf) {
            int nr = nf * 16 + lrow;
            short8 bfr = *reinterpret_cast<const short8*>(&W_lds[nr * 128 + ((kkl ^ (nr & 7)) << 3)]);
            acc[nf] = __builtin_amdgcn_mfma_f32_16x16x32_bf16(af, bfr, acc[nf], 0, 0, 0);
        }
    }

    // ---- epilogue: bias + leaky + row l2-norm; write fp32 out + bf16 next-x ----
    float bsv[8];
#pragma unroll
    for (int nf = 0; nf < 8; ++nf) bsv[nf] = bsum[nf * 16 + lrow];

#pragma unroll
    for (int reg = 0; reg < 4; ++reg) {
        int grow = row0 + w * 16 + kgrp * 4 + reg;
        float v[8];
        float ssq = 0.f;
#pragma unroll
        for (int nf = 0; nf < 8; ++nf) {
            float tv = acc[nf][reg] + bsv[nf];
            tv = tv > 0.f ? tv : ALPHA * tv;
            v[nf] = tv;
            ssq += tv * tv;
        }
        ssq += __shfl_xor(ssq, 1);
        ssq += __shfl_xor(ssq, 2);
        ssq += __shfl_xor(ssq, 4);
        ssq += __shfl_xor(ssq, 8);
        float sc = 1.0f / sqrtf(fmaxf(ssq, L2EPS));
        if (grow < n) {
            float* op = xout + (size_t)grow * LDO;
            unsigned short* bp = xb_out + (size_t)grow * ND;
#pragma unroll
            for (int nf = 0; nf < 8; ++nf) {
                float ov = v[nf] * sc;
                op[nf * 16 + lrow] = ov;
                bp[nf * 16 + lrow] = (unsigned short)f2bf(ov);
            }
        }
    }
}

extern "C" void kernel_launch(void* const* d_in, const int* in_sizes, int n_in,
                              void* d_out, int out_size, void* d_ws, size_t ws_size,
                              hipStream_t stream) {
    const float* emb  = (const float*)d_in[0];
    const int*   erow = (const int*)d_in[1];
    const int*   ecol = (const int*)d_in[2];
    const float* eval = (const float*)d_in[3];
    const float* Wgc  = (const float*)d_in[4];
    const float* bgc  = (const float*)d_in[5];
    const float* Wbi  = (const float*)d_in[6];
    const float* bbi  = (const float*)d_in[7];
    float* out = (float*)d_out;

    const int n        = in_sizes[0] / ND;      // 100000
    const int n_edges  = in_sizes[1];           // 1600000
    const int n_layers = in_sizes[5] / ND;      // 3

    const int nb = (n + RPB - 1) >> 9;          // 196 buckets
    const int ch = (n_edges + NCHUNK - 1) / NCHUNK;
    const int ng = nb * NCHUNK;

    // ---- workspace layout (256B-aligned) ----
    char* ws = (char*)d_ws;
    size_t off = 0;
    auto alloc = [&](size_t bytes) { void* p = ws + off; off = (off + bytes + 255) & ~(size_t)255; return p; };
    unsigned short* xb0 = (unsigned short*)alloc((size_t)n * ND * sizeof(short));   // 25.6 MB
    unsigned short* xb1 = (unsigned short*)alloc((size_t)n * ND * sizeof(short));   // 25.6 MB
    int2*  pv        = (int2*) alloc((size_t)n_edges * sizeof(int2));               // 12.8 MB
    int2*  tmp       = (int2*) alloc((size_t)n_edges * sizeof(int2));               // 12.8 MB
    int*   row_start = (int*)  alloc((size_t)(n + 1) * sizeof(int));
    int*   gcnt      = (int*)  alloc((size_t)ng * sizeof(int));
    int*   gbase     = (int*)  alloc((size_t)ng * sizeof(int));
    int*   partials  = (int*)  alloc(512 * sizeof(int));
    short* Wt2       = (short*)alloc((size_t)n_layers * 2 * 128 * 128 * sizeof(short));
    float* bsum      = (float*)alloc((size_t)n_layers * 128 * sizeof(float));
    (void)ws_size;

    // ---- x0 -> out[:, 0:128] + xb0 ----
    {
        int total = n * 32;
        copy_emb_kernel<<<(total + 255) / 256, 256, 0, stream>>>(emb, out, xb0, n);
    }

    // ---- weight prep ----
    {
        dim3 g(n_layers, 128);
        prep_w_kernel<<<g, 256, 0, stream>>>(Wgc, bgc, Wbi, bbi, Wt2, bsum);
    }

    // ---- CSR build ----
    bucket_hist_kernel<<<NCHUNK, 256, 0, stream>>>(erow, gcnt, n_edges, nb, ch);
    {
        int nblk = (ng + SCAN_B - 1) / SCAN_B;
        scanA_kernel<<<nblk, SCAN_B, 0, stream>>>(gcnt, gbase, partials, ng);
        scanB_kernel<<<1, 512, 0, stream>>>(partials, nblk);
        scan_add_kernel<<<(ng + 255) / 256, 256, 0, stream>>>(gbase, partials, ng);
    }
    bucket_scatter_kernel<<<NCHUNK, 256, 0, stream>>>(erow, ecol, eval, gbase, tmp, n_edges, nb, ch);
    bucket_sort_kernel<<<nb, 256, 0, stream>>>(tmp, gbase, pv, row_start, n, n_edges, nb);

    // ---- layers (xb ping-pong: gather reads xb_in, epilogue writes xb_out) ----
    unsigned short* xbs[2] = {xb0, xb1};
    for (int i = 0; i < n_layers; ++i) {
        fused_spmm_layer<<<(n + 63) / 64, 256, 0, stream>>>(
            row_start, pv, xbs[i & 1],
            Wt2 + (size_t)i * 2 * 128 * 128, bsum + (size_t)i * 128,
            out + (size_t)(i + 1) * ND, xbs[(i + 1) & 1], n);
    }
}

// Round 8
// 397.720 us; speedup vs baseline: 1.6486x; 1.6486x over previous
//
#include <hip/hip_runtime.h>
#include <hip/hip_bf16.h>

#define ND 128
#define LDO 512
#define ALPHA 0.2f
#define L2EPS 1e-12f
#define SCAN_B 256
#define NCHUNK 256     // edge chunks for bucket hist/scatter
#define RPB 512        // rows per bucket (shift 9)

typedef __attribute__((ext_vector_type(8))) short short8;
typedef __attribute__((ext_vector_type(4))) float f32x4;

__device__ __forceinline__ short f2bf(float f) {
    union { float f; unsigned u; } c; c.f = f;
    unsigned u = c.u;
    unsigned r = (u + 0x7fffu + ((u >> 16) & 1u)) >> 16;   // RNE
    return (short)r;
}
__device__ __forceinline__ float bf2f(unsigned short u) {
    union { unsigned u; float f; } c; c.u = ((unsigned)u) << 16;
    return c.f;
}
__device__ __forceinline__ void gload_lds16(const void* g, void* l) {
    __builtin_amdgcn_global_load_lds(
        (const __attribute__((address_space(1))) unsigned int*)g,
        (__attribute__((address_space(3))) unsigned int*)l, 16, 0, 0);
}

// ---------------- copy embeddings into out[:, 0:128] and xb ----------------
__global__ void copy_emb_kernel(const float* __restrict__ emb, float* __restrict__ out,
                                unsigned short* __restrict__ xb, int n) {
    int idx = blockIdx.x * blockDim.x + threadIdx.x;
    int total = n * 32;
    if (idx >= total) return;
    int r = idx >> 5, c4 = idx & 31;
    const float4 v = *reinterpret_cast<const float4*>(emb + (size_t)r * ND + c4 * 4);
    *reinterpret_cast<float4*>(out + (size_t)r * LDO + c4 * 4) = v;
    ushort4 b;
    b.x = (unsigned short)f2bf(v.x); b.y = (unsigned short)f2bf(v.y);
    b.z = (unsigned short)f2bf(v.z); b.w = (unsigned short)f2bf(v.w);
    *reinterpret_cast<ushort4*>(xb + (size_t)r * ND + c4 * 4) = b;
}

// ---------------- pass A: per-chunk bucket histogram (LDS only) ----------------
__global__ __launch_bounds__(256) void bucket_hist_kernel(const int* __restrict__ erow,
                                                          int* __restrict__ gcnt,
                                                          int n_edges, int nb, int ch) {
    __shared__ int cnt[256];
    int b = blockIdx.x;
    cnt[threadIdx.x] = 0;
    __syncthreads();
    int s = b * ch, e = min(n_edges, s + ch);
    for (int j = s + threadIdx.x; j < e; j += 256) {
        atomicAdd(&cnt[erow[j] >> 9], 1);
    }
    __syncthreads();
    for (int i = threadIdx.x; i < nb; i += 256) gcnt[i * NCHUNK + b] = cnt[i];
}

// ---------------- scans ----------------
__global__ __launch_bounds__(SCAN_B) void scanA_kernel(const int* __restrict__ in,
                                                       int* __restrict__ outp,
                                                       int* __restrict__ partials, int n) {
    __shared__ int sm[SCAN_B];
    int i = blockIdx.x * SCAN_B + threadIdx.x;
    int v = (i < n) ? in[i] : 0;
    sm[threadIdx.x] = v;
    __syncthreads();
#pragma unroll
    for (int off = 1; off < SCAN_B; off <<= 1) {
        int t = (threadIdx.x >= off) ? sm[threadIdx.x - off] : 0;
        __syncthreads();
        sm[threadIdx.x] += t;
        __syncthreads();
    }
    if (i < n) outp[i] = sm[threadIdx.x] - v;
    if (threadIdx.x == SCAN_B - 1) partials[blockIdx.x] = sm[SCAN_B - 1];
}

__global__ __launch_bounds__(512) void scanB_kernel(int* __restrict__ partials, int nb) {
    __shared__ int sm[512];
    int v = (threadIdx.x < nb) ? partials[threadIdx.x] : 0;
    sm[threadIdx.x] = v;
    __syncthreads();
#pragma unroll
    for (int off = 1; off < 512; off <<= 1) {
        int t = (threadIdx.x >= off) ? sm[threadIdx.x - off] : 0;
        __syncthreads();
        sm[threadIdx.x] += t;
        __syncthreads();
    }
    if (threadIdx.x < nb) partials[threadIdx.x] = sm[threadIdx.x] - v;
}

__global__ void scan_add_kernel(int* __restrict__ arr, const int* __restrict__ partials, int n) {
    int i = blockIdx.x * blockDim.x + threadIdx.x;
    if (i < n) arr[i] += partials[i >> 8];
}

// ---------------- pass B: scatter into bucket-grouped tmp (coalesced runs) ----------------
__global__ __launch_bounds__(256) void bucket_scatter_kernel(const int* __restrict__ erow,
                                                             const int* __restrict__ ecol,
                                                             const float* __restrict__ eval,
                                                             const int* __restrict__ gbase,
                                                             int2* __restrict__ tmp,
                                                             int n_edges, int nb, int ch) {
    __shared__ int cur[256];
    int b = blockIdx.x;
    for (int i = threadIdx.x; i < nb; i += 256) cur[i] = gbase[i * NCHUNK + b];
    __syncthreads();
    int s = b * ch, e = min(n_edges, s + ch);
    for (int j = s + threadIdx.x; j < e; j += 256) {
        int r = erow[j];
        int pos = atomicAdd(&cur[r >> 9], 1);
        int2 p;
        p.x = ecol[j] | ((r & (RPB - 1)) << 17);     // col (17b) | row-low (9b)
        p.y = __float_as_int(eval[j]);
        tmp[pos] = p;
    }
}

// ---------------- pass C: per-bucket counting sort into final CSR pv + row_start ----------
__global__ __launch_bounds__(256) void bucket_sort_kernel(const int2* __restrict__ tmp,
                                                          const int* __restrict__ gbase,
                                                          int2* __restrict__ pv,
                                                          int* __restrict__ row_start,
                                                          int n, int n_edges, int nb) {
    __shared__ int hist[RPB];
    __shared__ int cur[RPB];
    __shared__ int sc[256];
    const int t = threadIdx.x;
    const int bkt = blockIdx.x;
    const int r0 = bkt << 9;
    const int s = gbase[bkt * NCHUNK];
    const int e = (bkt + 1 < nb) ? gbase[(bkt + 1) * NCHUNK] : n_edges;

    for (int i = t; i < RPB; i += 256) hist[i] = 0;
    __syncthreads();
    for (int j = s + t; j < e; j += 256) atomicAdd(&hist[tmp[j].x >> 17], 1);
    __syncthreads();
    int a0 = hist[2 * t], a1 = hist[2 * t + 1];
    sc[t] = a0 + a1;
    __syncthreads();
#pragma unroll
    for (int off = 1; off < 256; off <<= 1) {
        int v = (t >= off) ? sc[t - off] : 0;
        __syncthreads();
        sc[t] += v;
        __syncthreads();
    }
    int base = s + sc[t] - a0 - a1;
    cur[2 * t] = base;
    cur[2 * t + 1] = base + a0;
    __syncthreads();
    int r1 = min(n, r0 + RPB);
    for (int i = t; i < r1 - r0; i += 256) row_start[r0 + i] = cur[i];
    if (t == 0 && r1 == n) row_start[n] = n_edges;
    __syncthreads();
    for (int j = s + t; j < e; j += 256) {
        int2 p = tmp[j];
        int pos = atomicAdd(&cur[p.x >> 17], 1);
        int2 q;
        q.x = p.x & 0x1FFFF;
        q.y = p.y;
        pv[pos] = q;
    }
}

// ---------------- SPMM + prop/xm formation, pre-swizzled bf16 Axm ----------------
// 16 lanes per row (ushort8 = 16B per lane), 16 rows per 256-thread block.
// Axm row = 512B = [pr(16 chunks) | xm(16 chunks)], chunk c stored at (c^(r&7))
__global__ __launch_bounds__(256) void spmm_axm_kernel(const int* __restrict__ row_start,
                                                       const int2* __restrict__ pv,
                                                       const unsigned short* __restrict__ xb,
                                                       unsigned short* __restrict__ Axm, int n) {
    int r = blockIdx.x * 16 + (threadIdx.x >> 4);
    if (r >= n) return;
    int l = threadIdx.x & 15;        // lane within row; elems l*8 .. l*8+7
    int s = row_start[r], e = row_start[r + 1];
    float a[8] = {0.f, 0.f, 0.f, 0.f, 0.f, 0.f, 0.f, 0.f};
    int j = s;
    for (; j + 3 < e; j += 4) {
        int2 p0 = pv[j], p1 = pv[j + 1], p2 = pv[j + 2], p3 = pv[j + 3];
        float v0 = __int_as_float(p0.y), v1 = __int_as_float(p1.y);
        float v2 = __int_as_float(p2.y), v3 = __int_as_float(p3.y);
        short8 x0 = *reinterpret_cast<const short8*>(xb + (size_t)p0.x * ND + l * 8);
        short8 x1 = *reinterpret_cast<const short8*>(xb + (size_t)p1.x * ND + l * 8);
        short8 x2 = *reinterpret_cast<const short8*>(xb + (size_t)p2.x * ND + l * 8);
        short8 x3 = *reinterpret_cast<const short8*>(xb + (size_t)p3.x * ND + l * 8);
#pragma unroll
        for (int q = 0; q < 8; ++q) {
            a[q] += v0 * bf2f((unsigned short)x0[q]) + v1 * bf2f((unsigned short)x1[q])
                  + v2 * bf2f((unsigned short)x2[q]) + v3 * bf2f((unsigned short)x3[q]);
        }
    }
    for (; j < e; ++j) {
        int2 p0 = pv[j];
        float v0 = __int_as_float(p0.y);
        short8 x0 = *reinterpret_cast<const short8*>(xb + (size_t)p0.x * ND + l * 8);
#pragma unroll
        for (int q = 0; q < 8; ++q) a[q] += v0 * bf2f((unsigned short)x0[q]);
    }
    // own x row (streaming)
    short8 xv = *reinterpret_cast<const short8*>(xb + (size_t)r * ND + l * 8);
    short8 prv, xmv;
#pragma unroll
    for (int q = 0; q < 8; ++q) {
        float xf = bf2f((unsigned short)xv[q]);
        prv[q] = f2bf(xf + a[q]);
        xmv[q] = f2bf(xf * a[q]);
    }
    int sz = r & 7;
    unsigned short* rowp = Axm + (size_t)r * 256;
    *reinterpret_cast<short8*>(rowp + ((l        ^ sz) << 3)) = prv;
    *reinterpret_cast<short8*>(rowp + (((16 + l) ^ sz) << 3)) = xmv;
}

// ---------------- prep: Wt2[layer][h][nr][..] pre-swizzled bf16, bsum = bgc+bbi ----------
__global__ void prep_w_kernel(const float* __restrict__ Wgc, const float* __restrict__ bgc,
                              const float* __restrict__ Wbi, const float* __restrict__ bbi,
                              short* __restrict__ Wt2, float* __restrict__ bsum) {
    int z = blockIdx.x;
    int k = blockIdx.y;            // K index within half, 0..127
    int t = threadIdx.x;
    int nn = t & 127;              // N index
    int h  = (t < 128) ? 0 : 1;    // half 0 = Wgc (prop), 1 = Wbi (xm)
    const float* src = h ? (Wbi + ((size_t)z * 128 + k) * 128)
                         : (Wgc + ((size_t)z * 128 + k) * 128);
    float v = src[nn];
    int idx16 = k >> 3, e8 = k & 7;
    size_t addr = ((size_t)(z * 2 + h) * 128 + nn) * 128 + ((idx16 ^ (nn & 7)) << 3) + e8;
    Wt2[addr] = f2bf(v);
    if (k == 0 && t < 128) bsum[z * 128 + t] = bgc[z * 128 + t] + bbi[z * 128 + t];
}

// ---------------- fused layer via MFMA (pure-copy staging) ----------------
__global__ __launch_bounds__(256) void fused_layer_mfma(
        const unsigned short* __restrict__ Axm,   // [(n+pad)][256] pre-swizzled
        const short* __restrict__ Wt2,            // [2][128][128] pre-swizzled (layer base)
        const float* __restrict__ bsum,           // [128]
        float* __restrict__ xout,                 // row stride LDO (fp32 out slice)
        unsigned short* __restrict__ xbout,       // [n][128] bf16 shadow (next x)
        int n) {
    __shared__ short A_lds[64 * 256];    // 32 KB
    __shared__ short W_lds[128 * 128];   // 32 KB

    const int tid  = threadIdx.x;
    const int row0 = blockIdx.x * 64;
    const int lane = tid & 63;
    const int w    = tid >> 6;
    const int lrow = lane & 15;
    const int kgrp = lane >> 4;

    // ---- async stage: A tile (32KB) + W half 0 (32KB), both LDS-linear copies ----
    {
        const char* gA = (const char*)(Axm + (size_t)row0 * 256) + w * 8192 + lane * 16;
        char*       lA = (char*)A_lds + w * 8192;
        const char* gW = (const char*)Wt2 + w * 8192 + lane * 16;
        char*       lW = (char*)W_lds + w * 8192;
#pragma unroll
        for (int it = 0; it < 8; ++it) {
            gload_lds16(gA + it * 1024, lA + it * 1024);
            gload_lds16(gW + it * 1024, lW + it * 1024);
        }
    }
    asm volatile("s_waitcnt vmcnt(0)" ::: "memory");
    __syncthreads();

    f32x4 acc[8];
#pragma unroll
    for (int nf = 0; nf < 8; ++nf) acc[nf] = (f32x4){0.f, 0.f, 0.f, 0.f};

    const int ar  = w * 16 + lrow;
    const int as_ = ar & 7;

    // ---- half 0 (prop @ Wgc) ----
#pragma unroll
    for (int ksl = 0; ksl < 4; ++ksl) {
        int kkl = ksl * 4 + kgrp;                    // 0..15
        short8 af = *reinterpret_cast<const short8*>(&A_lds[ar * 256 + ((kkl ^ as_) << 3)]);
#pragma unroll
        for (int nf = 0; nf < 8; ++nf) {
            int nr = nf * 16 + lrow;
            short8 bfr = *reinterpret_cast<const short8*>(&W_lds[nr * 128 + ((kkl ^ (nr & 7)) << 3)]);
            acc[nf] = __builtin_amdgcn_mfma_f32_16x16x32_bf16(af, bfr, acc[nf], 0, 0, 0);
        }
    }
    __syncthreads();
    // ---- stage W half 1 ----
    {
        const char* gW = (const char*)Wt2 + 32768 + w * 8192 + lane * 16;
        char*       lW = (char*)W_lds + w * 8192;
#pragma unroll
        for (int it = 0; it < 8; ++it) gload_lds16(gW + it * 1024, lW + it * 1024);
    }
    asm volatile("s_waitcnt vmcnt(0)" ::: "memory");
    __syncthreads();

    // ---- half 1 (xm @ Wbi) ----
#pragma unroll
    for (int ksl = 0; ksl < 4; ++ksl) {
        int kkl = ksl * 4 + kgrp;
        short8 af = *reinterpret_cast<const short8*>(&A_lds[ar * 256 + (((16 + kkl) ^ as_) << 3)]);
#pragma unroll
        for (int nf = 0; nf < 8; ++nf) {
            int nr = nf * 16 + lrow;
            short8 bfr = *reinterpret_cast<const short8*>(&W_lds[nr * 128 + ((kkl ^ (nr & 7)) << 3)]);
            acc[nf] = __builtin_amdgcn_mfma_f32_16x16x32_bf16(af, bfr, acc[nf], 0, 0, 0);
        }
    }

    // ---- epilogue: bias + leaky + row l2-norm; write fp32 out + bf16 shadow ----
    float bsv[8];
#pragma unroll
    for (int nf = 0; nf < 8; ++nf) bsv[nf] = bsum[nf * 16 + lrow];

#pragma unroll
    for (int reg = 0; reg < 4; ++reg) {
        int grow = row0 + w * 16 + kgrp * 4 + reg;
        float v[8];
        float ssq = 0.f;
#pragma unroll
        for (int nf = 0; nf < 8; ++nf) {
            float tv = acc[nf][reg] + bsv[nf];
            tv = tv > 0.f ? tv : ALPHA * tv;
            v[nf] = tv;
            ssq += tv * tv;
        }
        ssq += __shfl_xor(ssq, 1);
        ssq += __shfl_xor(ssq, 2);
        ssq += __shfl_xor(ssq, 4);
        ssq += __shfl_xor(ssq, 8);
        float sc = 1.0f / sqrtf(fmaxf(ssq, L2EPS));
        if (grow < n) {
            float* op = xout + (size_t)grow * LDO;
            unsigned short* bp = xbout + (size_t)grow * ND;
#pragma unroll
            for (int nf = 0; nf < 8; ++nf) {
                float ov = v[nf] * sc;
                op[nf * 16 + lrow] = ov;
                bp[nf * 16 + lrow] = (unsigned short)f2bf(ov);
            }
        }
    }
}

extern "C" void kernel_launch(void* const* d_in, const int* in_sizes, int n_in,
                              void* d_out, int out_size, void* d_ws, size_t ws_size,
                              hipStream_t stream) {
    const float* emb  = (const float*)d_in[0];
    const int*   erow = (const int*)d_in[1];
    const int*   ecol = (const int*)d_in[2];
    const float* eval = (const float*)d_in[3];
    const float* Wgc  = (const float*)d_in[4];
    const float* bgc  = (const float*)d_in[5];
    const float* Wbi  = (const float*)d_in[6];
    const float* bbi  = (const float*)d_in[7];
    float* out = (float*)d_out;

    const int n        = in_sizes[0] / ND;      // 100000
    const int n_edges  = in_sizes[1];           // 1600000
    const int n_layers = in_sizes[5] / ND;      // 3

    const int nb = (n + RPB - 1) >> 9;          // 196 buckets
    const int ch = (n_edges + NCHUNK - 1) / NCHUNK;
    const int ng = nb * NCHUNK;

    // ---- workspace layout (256B-aligned) ----
    char* ws = (char*)d_ws;
    size_t off = 0;
    auto alloc = [&](size_t bytes) { void* p = ws + off; off = (off + bytes + 255) & ~(size_t)255; return p; };
    unsigned short* xb  = (unsigned short*)alloc((size_t)n * ND * sizeof(short));        // 25.6 MB
    unsigned short* Axm = (unsigned short*)alloc((size_t)(n + 64) * 256 * sizeof(short)); // 51.2 MB (+pad)
    int2*  pv        = (int2*) alloc((size_t)n_edges * sizeof(int2));                    // 12.8 MB
    int2*  tmp       = (int2*) alloc((size_t)n_edges * sizeof(int2));                    // 12.8 MB
    int*   row_start = (int*)  alloc((size_t)(n + 1) * sizeof(int));
    int*   gcnt      = (int*)  alloc((size_t)ng * sizeof(int));
    int*   gbase     = (int*)  alloc((size_t)ng * sizeof(int));
    int*   partials  = (int*)  alloc(512 * sizeof(int));
    short* Wt2       = (short*)alloc((size_t)n_layers * 2 * 128 * 128 * sizeof(short));
    float* bsum      = (float*)alloc((size_t)n_layers * 128 * sizeof(float));
    (void)ws_size;

    // ---- x0 -> out[:, 0:128] + xb ----
    {
        int total = n * 32;
        copy_emb_kernel<<<(total + 255) / 256, 256, 0, stream>>>(emb, out, xb, n);
    }

    // ---- weight prep ----
    {
        dim3 g(n_layers, 128);
        prep_w_kernel<<<g, 256, 0, stream>>>(Wgc, bgc, Wbi, bbi, Wt2, bsum);
    }

    // ---- CSR build ----
    bucket_hist_kernel<<<NCHUNK, 256, 0, stream>>>(erow, gcnt, n_edges, nb, ch);
    {
        int nblk = (ng + SCAN_B - 1) / SCAN_B;
        scanA_kernel<<<nblk, SCAN_B, 0, stream>>>(gcnt, gbase, partials, ng);
        scanB_kernel<<<1, 512, 0, stream>>>(partials, nblk);
        scan_add_kernel<<<(ng + 255) / 256, 256, 0, stream>>>(gbase, partials, ng);
    }
    bucket_scatter_kernel<<<NCHUNK, 256, 0, stream>>>(erow, ecol, eval, gbase, tmp, n_edges, nb, ch);
    bucket_sort_kernel<<<nb, 256, 0, stream>>>(tmp, gbase, pv, row_start, n, n_edges, nb);

    // ---- layers ----
    for (int i = 0; i < n_layers; ++i) {
        spmm_axm_kernel<<<(n + 15) / 16, 256, 0, stream>>>(row_start, pv, xb, Axm, n);
        fused_layer_mfma<<<(n + 63) / 64, 256, 0, stream>>>(
            Axm, Wt2 + (size_t)i * 2 * 128 * 128, bsum + (size_t)i * 128,
            out + (size_t)(i + 1) * ND, xb, n);
    }
}

// Round 9
// 355.612 us; speedup vs baseline: 1.8438x; 1.1184x over previous
//
#include <hip/hip_runtime.h>
#include <hip/hip_bf16.h>

#define ND 128
#define LDO 512
#define ALPHA 0.2f
#define L2EPS 1e-12f
#define SCAN_B 256
#define NCHUNK 256     // edge chunks for bucket hist/scatter
#define RPB 512        // rows per bucket (shift 9)

typedef __attribute__((ext_vector_type(8))) short short8;
typedef __attribute__((ext_vector_type(4))) float f32x4;
typedef __attribute__((ext_vector_type(2))) float f32x2;

__device__ __forceinline__ short f2bf(float f) {
    union { float f; unsigned u; } c; c.f = f;
    unsigned u = c.u;
    unsigned r = (u + 0x7fffu + ((u >> 16) & 1u)) >> 16;   // RNE
    return (short)r;
}
__device__ __forceinline__ float bf2f(unsigned short u) {
    union { unsigned u; float f; } c; c.u = ((unsigned)u) << 16;
    return c.f;
}
__device__ __forceinline__ void gload_lds16(const void* g, void* l) {
    __builtin_amdgcn_global_load_lds(
        (const __attribute__((address_space(1))) unsigned int*)g,
        (__attribute__((address_space(3))) unsigned int*)l, 16, 0, 0);
}

// ---------------- copy embeddings into out[:, 0:128], xb (bf16), xf8 (fp8) ----------------
__global__ void copy_emb_kernel(const float* __restrict__ emb, float* __restrict__ out,
                                unsigned short* __restrict__ xb,
                                unsigned int* __restrict__ xf8w, int n) {
    int idx = blockIdx.x * blockDim.x + threadIdx.x;
    int total = n * 32;
    if (idx >= total) return;
    int r = idx >> 5, c4 = idx & 31;
    const float4 v = *reinterpret_cast<const float4*>(emb + (size_t)r * ND + c4 * 4);
    *reinterpret_cast<float4*>(out + (size_t)r * LDO + c4 * 4) = v;
    ushort4 b;
    b.x = (unsigned short)f2bf(v.x); b.y = (unsigned short)f2bf(v.y);
    b.z = (unsigned short)f2bf(v.z); b.w = (unsigned short)f2bf(v.w);
    *reinterpret_cast<ushort4*>(xb + (size_t)r * ND + c4 * 4) = b;
    unsigned int u = __builtin_amdgcn_cvt_pk_fp8_f32(v.x, v.y, 0, false);
    u = __builtin_amdgcn_cvt_pk_fp8_f32(v.z, v.w, u, true);
    xf8w[(size_t)r * 32 + c4] = u;
}

// ---------------- pass A: per-chunk bucket histogram (LDS only) ----------------
__global__ __launch_bounds__(256) void bucket_hist_kernel(const int* __restrict__ erow,
                                                          int* __restrict__ gcnt,
                                                          int n_edges, int nb, int ch) {
    __shared__ int cnt[256];
    int b = blockIdx.x;
    cnt[threadIdx.x] = 0;
    __syncthreads();
    int s = b * ch, e = min(n_edges, s + ch);
    for (int j = s + threadIdx.x; j < e; j += 256) {
        atomicAdd(&cnt[erow[j] >> 9], 1);
    }
    __syncthreads();
    for (int i = threadIdx.x; i < nb; i += 256) gcnt[i * NCHUNK + b] = cnt[i];
}

// ---------------- scans ----------------
__global__ __launch_bounds__(SCAN_B) void scanA_kernel(const int* __restrict__ in,
                                                       int* __restrict__ outp,
                                                       int* __restrict__ partials, int n) {
    __shared__ int sm[SCAN_B];
    int i = blockIdx.x * SCAN_B + threadIdx.x;
    int v = (i < n) ? in[i] : 0;
    sm[threadIdx.x] = v;
    __syncthreads();
#pragma unroll
    for (int off = 1; off < SCAN_B; off <<= 1) {
        int t = (threadIdx.x >= off) ? sm[threadIdx.x - off] : 0;
        __syncthreads();
        sm[threadIdx.x] += t;
        __syncthreads();
    }
    if (i < n) outp[i] = sm[threadIdx.x] - v;
    if (threadIdx.x == SCAN_B - 1) partials[blockIdx.x] = sm[SCAN_B - 1];
}

__global__ __launch_bounds__(512) void scanB_kernel(int* __restrict__ partials, int nb) {
    __shared__ int sm[512];
    int v = (threadIdx.x < nb) ? partials[threadIdx.x] : 0;
    sm[threadIdx.x] = v;
    __syncthreads();
#pragma unroll
    for (int off = 1; off < 512; off <<= 1) {
        int t = (threadIdx.x >= off) ? sm[threadIdx.x - off] : 0;
        __syncthreads();
        sm[threadIdx.x] += t;
        __syncthreads();
    }
    if (threadIdx.x < nb) partials[threadIdx.x] = sm[threadIdx.x] - v;
}

__global__ void scan_add_kernel(int* __restrict__ arr, const int* __restrict__ partials, int n) {
    int i = blockIdx.x * blockDim.x + threadIdx.x;
    if (i < n) arr[i] += partials[i >> 8];
}

// ---------------- pass B: scatter into bucket-grouped tmp (coalesced runs) ----------------
__global__ __launch_bounds__(256) void bucket_scatter_kernel(const int* __restrict__ erow,
                                                             const int* __restrict__ ecol,
                                                             const float* __restrict__ eval,
                                                             const int* __restrict__ gbase,
                                                             int2* __restrict__ tmp,
                                                             int n_edges, int nb, int ch) {
    __shared__ int cur[256];
    int b = blockIdx.x;
    for (int i = threadIdx.x; i < nb; i += 256) cur[i] = gbase[i * NCHUNK + b];
    __syncthreads();
    int s = b * ch, e = min(n_edges, s + ch);
    for (int j = s + threadIdx.x; j < e; j += 256) {
        int r = erow[j];
        int pos = atomicAdd(&cur[r >> 9], 1);
        int2 p;
        p.x = ecol[j] | ((r & (RPB - 1)) << 17);     // col (17b) | row-low (9b)
        p.y = __float_as_int(eval[j]);
        tmp[pos] = p;
    }
}

// ---------------- pass C: per-bucket counting sort into final CSR pv + row_start ----------
__global__ __launch_bounds__(256) void bucket_sort_kernel(const int2* __restrict__ tmp,
                                                          const int* __restrict__ gbase,
                                                          int2* __restrict__ pv,
                                                          int* __restrict__ row_start,
                                                          int n, int n_edges, int nb) {
    __shared__ int hist[RPB];
    __shared__ int cur[RPB];
    __shared__ int sc[256];
    const int t = threadIdx.x;
    const int bkt = blockIdx.x;
    const int r0 = bkt << 9;
    const int s = gbase[bkt * NCHUNK];
    const int e = (bkt + 1 < nb) ? gbase[(bkt + 1) * NCHUNK] : n_edges;

    for (int i = t; i < RPB; i += 256) hist[i] = 0;
    __syncthreads();
    for (int j = s + t; j < e; j += 256) atomicAdd(&hist[tmp[j].x >> 17], 1);
    __syncthreads();
    int a0 = hist[2 * t], a1 = hist[2 * t + 1];
    sc[t] = a0 + a1;
    __syncthreads();
#pragma unroll
    for (int off = 1; off < 256; off <<= 1) {
        int v = (t >= off) ? sc[t - off] : 0;
        __syncthreads();
        sc[t] += v;
        __syncthreads();
    }
    int base = s + sc[t] - a0 - a1;
    cur[2 * t] = base;
    cur[2 * t + 1] = base + a0;
    __syncthreads();
    int r1 = min(n, r0 + RPB);
    for (int i = t; i < r1 - r0; i += 256) row_start[r0 + i] = cur[i];
    if (t == 0 && r1 == n) row_start[n] = n_edges;
    __syncthreads();
    for (int j = s + t; j < e; j += 256) {
        int2 p = tmp[j];
        int pos = atomicAdd(&cur[p.x >> 17], 1);
        int2 q;
        q.x = p.x & 0x1FFFF;
        q.y = p.y;
        pv[pos] = q;
    }
}

// ---------------- SPMM (fp8 gather) + prop/xm formation, pre-swizzled bf16 Axm ----------
// 16 lanes per row (uint2 = 8 fp8 per lane), 16 rows per 256-thread block.
// Axm row = 512B = [pr(16 chunks) | xm(16 chunks)], chunk c stored at (c^(r&7))
__global__ __launch_bounds__(256) void spmm_axm_kernel(const int* __restrict__ row_start,
                                                       const int2* __restrict__ pv,
                                                       const unsigned char* __restrict__ xf8,
                                                       const unsigned short* __restrict__ xb,
                                                       unsigned short* __restrict__ Axm, int n) {
    int r = blockIdx.x * 16 + (threadIdx.x >> 4);
    if (r >= n) return;
    int l = threadIdx.x & 15;        // lane within row; elems l*8 .. l*8+7
    int s = row_start[r], e = row_start[r + 1];
    float a[8] = {0.f, 0.f, 0.f, 0.f, 0.f, 0.f, 0.f, 0.f};
    int j = s;
    for (; j + 1 < e; j += 2) {
        int2 p0 = pv[j], p1 = pv[j + 1];
        float v0 = __int_as_float(p0.y), v1 = __int_as_float(p1.y);
        uint2 q0 = *reinterpret_cast<const uint2*>(xf8 + (size_t)p0.x * ND + l * 8);
        uint2 q1 = *reinterpret_cast<const uint2*>(xf8 + (size_t)p1.x * ND + l * 8);
        f32x2 g0 = __builtin_amdgcn_cvt_pk_f32_fp8(q0.x, false);
        f32x2 g1 = __builtin_amdgcn_cvt_pk_f32_fp8(q0.x, true);
        f32x2 g2 = __builtin_amdgcn_cvt_pk_f32_fp8(q0.y, false);
        f32x2 g3 = __builtin_amdgcn_cvt_pk_f32_fp8(q0.y, true);
        f32x2 h0 = __builtin_amdgcn_cvt_pk_f32_fp8(q1.x, false);
        f32x2 h1 = __builtin_amdgcn_cvt_pk_f32_fp8(q1.x, true);
        f32x2 h2 = __builtin_amdgcn_cvt_pk_f32_fp8(q1.y, false);
        f32x2 h3 = __builtin_amdgcn_cvt_pk_f32_fp8(q1.y, true);
        a[0] += v0 * g0.x + v1 * h0.x;
        a[1] += v0 * g0.y + v1 * h0.y;
        a[2] += v0 * g1.x + v1 * h1.x;
        a[3] += v0 * g1.y + v1 * h1.y;
        a[4] += v0 * g2.x + v1 * h2.x;
        a[5] += v0 * g2.y + v1 * h2.y;
        a[6] += v0 * g3.x + v1 * h3.x;
        a[7] += v0 * g3.y + v1 * h3.y;
    }
    if (j < e) {
        int2 p0 = pv[j];
        float v0 = __int_as_float(p0.y);
        uint2 q0 = *reinterpret_cast<const uint2*>(xf8 + (size_t)p0.x * ND + l * 8);
        f32x2 g0 = __builtin_amdgcn_cvt_pk_f32_fp8(q0.x, false);
        f32x2 g1 = __builtin_amdgcn_cvt_pk_f32_fp8(q0.x, true);
        f32x2 g2 = __builtin_amdgcn_cvt_pk_f32_fp8(q0.y, false);
        f32x2 g3 = __builtin_amdgcn_cvt_pk_f32_fp8(q0.y, true);
        a[0] += v0 * g0.x; a[1] += v0 * g0.y;
        a[2] += v0 * g1.x; a[3] += v0 * g1.y;
        a[4] += v0 * g2.x; a[5] += v0 * g2.y;
        a[6] += v0 * g3.x; a[7] += v0 * g3.y;
    }
    // own x row (streaming, bf16 precision)
    short8 xv = *reinterpret_cast<const short8*>(xb + (size_t)r * ND + l * 8);
    short8 prv, xmv;
#pragma unroll
    for (int q = 0; q < 8; ++q) {
        float xf = bf2f((unsigned short)xv[q]);
        prv[q] = f2bf(xf + a[q]);
        xmv[q] = f2bf(xf * a[q]);
    }
    int sz = r & 7;
    unsigned short* rowp = Axm + (size_t)r * 256;
    *reinterpret_cast<short8*>(rowp + ((l        ^ sz) << 3)) = prv;
    *reinterpret_cast<short8*>(rowp + (((16 + l) ^ sz) << 3)) = xmv;
}

// ---------------- prep: Wt2[layer][h][nr][..] pre-swizzled bf16, bsum = bgc+bbi ----------
__global__ void prep_w_kernel(const float* __restrict__ Wgc, const float* __restrict__ bgc,
                              const float* __restrict__ Wbi, const float* __restrict__ bbi,
                              short* __restrict__ Wt2, float* __restrict__ bsum) {
    int z = blockIdx.x;
    int k = blockIdx.y;            // K index within half, 0..127
    int t = threadIdx.x;
    int nn = t & 127;              // N index
    int h  = (t < 128) ? 0 : 1;    // half 0 = Wgc (prop), 1 = Wbi (xm)
    const float* src = h ? (Wbi + ((size_t)z * 128 + k) * 128)
                         : (Wgc + ((size_t)z * 128 + k) * 128);
    float v = src[nn];
    int idx16 = k >> 3, e8 = k & 7;
    size_t addr = ((size_t)(z * 2 + h) * 128 + nn) * 128 + ((idx16 ^ (nn & 7)) << 3) + e8;
    Wt2[addr] = f2bf(v);
    if (k == 0 && t < 128) bsum[z * 128 + t] = bgc[z * 128 + t] + bbi[z * 128 + t];
}

// ---------------- fused layer via MFMA (pure-copy staging) ----------------
__global__ __launch_bounds__(256) void fused_layer_mfma(
        const unsigned short* __restrict__ Axm,   // [(n+pad)][256] pre-swizzled
        const short* __restrict__ Wt2,            // [2][128][128] pre-swizzled (layer base)
        const float* __restrict__ bsum,           // [128]
        float* __restrict__ xout,                 // row stride LDO (fp32 out slice)
        unsigned short* __restrict__ xbout,       // [n][128] bf16 shadow (next x)
        unsigned char* __restrict__ xf8out,       // [n][128] fp8 shadow (next x)
        int n) {
    __shared__ short A_lds[64 * 256];    // 32 KB
    __shared__ short W_lds[128 * 128];   // 32 KB

    const int tid  = threadIdx.x;
    const int row0 = blockIdx.x * 64;
    const int lane = tid & 63;
    const int w    = tid >> 6;
    const int lrow = lane & 15;
    const int kgrp = lane >> 4;

    // ---- async stage: A tile (32KB) + W half 0 (32KB), both LDS-linear copies ----
    {
        const char* gA = (const char*)(Axm + (size_t)row0 * 256) + w * 8192 + lane * 16;
        char*       lA = (char*)A_lds + w * 8192;
        const char* gW = (const char*)Wt2 + w * 8192 + lane * 16;
        char*       lW = (char*)W_lds + w * 8192;
#pragma unroll
        for (int it = 0; it < 8; ++it) {
            gload_lds16(gA + it * 1024, lA + it * 1024);
            gload_lds16(gW + it * 1024, lW + it * 1024);
        }
    }
    asm volatile("s_waitcnt vmcnt(0)" ::: "memory");
    __syncthreads();

    f32x4 acc[8];
#pragma unroll
    for (int nf = 0; nf < 8; ++nf) acc[nf] = (f32x4){0.f, 0.f, 0.f, 0.f};

    const int ar  = w * 16 + lrow;
    const int as_ = ar & 7;

    // ---- half 0 (prop @ Wgc) ----
#pragma unroll
    for (int ksl = 0; ksl < 4; ++ksl) {
        int kkl = ksl * 4 + kgrp;                    // 0..15
        short8 af = *reinterpret_cast<const short8*>(&A_lds[ar * 256 + ((kkl ^ as_) << 3)]);
#pragma unroll
        for (int nf = 0; nf < 8; ++nf) {
            int nr = nf * 16 + lrow;
            short8 bfr = *reinterpret_cast<const short8*>(&W_lds[nr * 128 + ((kkl ^ (nr & 7)) << 3)]);
            acc[nf] = __builtin_amdgcn_mfma_f32_16x16x32_bf16(af, bfr, acc[nf], 0, 0, 0);
        }
    }
    __syncthreads();
    // ---- stage W half 1 ----
    {
        const char* gW = (const char*)Wt2 + 32768 + w * 8192 + lane * 16;
        char*       lW = (char*)W_lds + w * 8192;
#pragma unroll
        for (int it = 0; it < 8; ++it) gload_lds16(gW + it * 1024, lW + it * 1024);
    }
    asm volatile("s_waitcnt vmcnt(0)" ::: "memory");
    __syncthreads();

    // ---- half 1 (xm @ Wbi) ----
#pragma unroll
    for (int ksl = 0; ksl < 4; ++ksl) {
        int kkl = ksl * 4 + kgrp;
        short8 af = *reinterpret_cast<const short8*>(&A_lds[ar * 256 + (((16 + kkl) ^ as_) << 3)]);
#pragma unroll
        for (int nf = 0; nf < 8; ++nf) {
            int nr = nf * 16 + lrow;
            short8 bfr = *reinterpret_cast<const short8*>(&W_lds[nr * 128 + ((kkl ^ (nr & 7)) << 3)]);
            acc[nf] = __builtin_amdgcn_mfma_f32_16x16x32_bf16(af, bfr, acc[nf], 0, 0, 0);
        }
    }

    // ---- epilogue: bias + leaky + row l2-norm; write fp32 out + bf16 + fp8 shadows ----
    float bsv[8];
#pragma unroll
    for (int nf = 0; nf < 8; ++nf) bsv[nf] = bsum[nf * 16 + lrow];

#pragma unroll
    for (int reg = 0; reg < 4; ++reg) {
        int grow = row0 + w * 16 + kgrp * 4 + reg;
        float v[8];
        float ssq = 0.f;
#pragma unroll
        for (int nf = 0; nf < 8; ++nf) {
            float tv = acc[nf][reg] + bsv[nf];
            tv = tv > 0.f ? tv : ALPHA * tv;
            v[nf] = tv;
            ssq += tv * tv;
        }
        ssq += __shfl_xor(ssq, 1);
        ssq += __shfl_xor(ssq, 2);
        ssq += __shfl_xor(ssq, 4);
        ssq += __shfl_xor(ssq, 8);
        float sc = 1.0f / sqrtf(fmaxf(ssq, L2EPS));
        if (grow < n) {
            float* op = xout + (size_t)grow * LDO;
            unsigned short* bp = xbout + (size_t)grow * ND;
            unsigned char* fp = xf8out + (size_t)grow * ND;
#pragma unroll
            for (int nf = 0; nf < 8; ++nf) {
                float ov = v[nf] * sc;
                op[nf * 16 + lrow] = ov;
                bp[nf * 16 + lrow] = (unsigned short)f2bf(ov);
                unsigned int u8 = __builtin_amdgcn_cvt_pk_fp8_f32(ov, ov, 0, false);
                fp[nf * 16 + lrow] = (unsigned char)(u8 & 0xff);
            }
        }
    }
}

extern "C" void kernel_launch(void* const* d_in, const int* in_sizes, int n_in,
                              void* d_out, int out_size, void* d_ws, size_t ws_size,
                              hipStream_t stream) {
    const float* emb  = (const float*)d_in[0];
    const int*   erow = (const int*)d_in[1];
    const int*   ecol = (const int*)d_in[2];
    const float* eval = (const float*)d_in[3];
    const float* Wgc  = (const float*)d_in[4];
    const float* bgc  = (const float*)d_in[5];
    const float* Wbi  = (const float*)d_in[6];
    const float* bbi  = (const float*)d_in[7];
    float* out = (float*)d_out;

    const int n        = in_sizes[0] / ND;      // 100000
    const int n_edges  = in_sizes[1];           // 1600000
    const int n_layers = in_sizes[5] / ND;      // 3

    const int nb = (n + RPB - 1) >> 9;          // 196 buckets
    const int ch = (n_edges + NCHUNK - 1) / NCHUNK;
    const int ng = nb * NCHUNK;

    // ---- workspace layout (256B-aligned) ----
    char* ws = (char*)d_ws;
    size_t off = 0;
    auto alloc = [&](size_t bytes) { void* p = ws + off; off = (off + bytes + 255) & ~(size_t)255; return p; };
    unsigned short* xb  = (unsigned short*)alloc((size_t)n * ND * sizeof(short));        // 25.6 MB
    unsigned char*  xf8 = (unsigned char*) alloc((size_t)n * ND);                        // 12.8 MB
    unsigned short* Axm = (unsigned short*)alloc((size_t)(n + 64) * 256 * sizeof(short)); // 51.2 MB (+pad)
    int2*  pv        = (int2*) alloc((size_t)n_edges * sizeof(int2));                    // 12.8 MB
    int2*  tmp       = (int2*) alloc((size_t)n_edges * sizeof(int2));                    // 12.8 MB
    int*   row_start = (int*)  alloc((size_t)(n + 1) * sizeof(int));
    int*   gcnt      = (int*)  alloc((size_t)ng * sizeof(int));
    int*   gbase     = (int*)  alloc((size_t)ng * sizeof(int));
    int*   partials  = (int*)  alloc(512 * sizeof(int));
    short* Wt2       = (short*)alloc((size_t)n_layers * 2 * 128 * 128 * sizeof(short));
    float* bsum      = (float*)alloc((size_t)n_layers * 128 * sizeof(float));
    (void)ws_size;

    // ---- x0 -> out[:, 0:128] + xb + xf8 ----
    {
        int total = n * 32;
        copy_emb_kernel<<<(total + 255) / 256, 256, 0, stream>>>(emb, out, xb,
                                                                 (unsigned int*)xf8, n);
    }

    // ---- weight prep ----
    {
        dim3 g(n_layers, 128);
        prep_w_kernel<<<g, 256, 0, stream>>>(Wgc, bgc, Wbi, bbi, Wt2, bsum);
    }

    // ---- CSR build ----
    bucket_hist_kernel<<<NCHUNK, 256, 0, stream>>>(erow, gcnt, n_edges, nb, ch);
    {
        int nblk = (ng + SCAN_B - 1) / SCAN_B;
        scanA_kernel<<<nblk, SCAN_B, 0, stream>>>(gcnt, gbase, partials, ng);
        scanB_kernel<<<1, 512, 0, stream>>>(partials, nblk);
        scan_add_kernel<<<(ng + 255) / 256, 256, 0, stream>>>(gbase, partials, ng);
    }
    bucket_scatter_kernel<<<NCHUNK, 256, 0, stream>>>(erow, ecol, eval, gbase, tmp, n_edges, nb, ch);
    bucket_sort_kernel<<<nb, 256, 0, stream>>>(tmp, gbase, pv, row_start, n, n_edges, nb);

    // ---- layers ----
    for (int i = 0; i < n_layers; ++i) {
        spmm_axm_kernel<<<(n + 15) / 16, 256, 0, stream>>>(row_start, pv, xf8, xb, Axm, n);
        fused_layer_mfma<<<(n + 63) / 64, 256, 0, stream>>>(
            Axm, Wt2 + (size_t)i * 2 * 128 * 128, bsum + (size_t)i * 128,
            out + (size_t)(i + 1) * ND, xb, xf8, n);
    }
}

// Round 10
// 328.627 us; speedup vs baseline: 1.9952x; 1.0821x over previous
//
#include <hip/hip_runtime.h>
#include <hip/hip_bf16.h>

#define ND 128
#define LDO 512
#define ALPHA 0.2f
#define L2EPS 1e-12f
#define SCAN_B 256
#define NCHUNK 256     // edge chunks for bucket hist/scatter (== SCAN_B, relied upon!)
#define RPB 512        // rows per bucket (shift 9)

typedef __attribute__((ext_vector_type(8))) short short8;
typedef __attribute__((ext_vector_type(4))) float f32x4;
typedef __attribute__((ext_vector_type(2))) float f32x2;

__device__ __forceinline__ short f2bf(float f) {
    union { float f; unsigned u; } c; c.f = f;
    unsigned u = c.u;
    unsigned r = (u + 0x7fffu + ((u >> 16) & 1u)) >> 16;   // RNE
    return (short)r;
}
__device__ __forceinline__ float bf2f(unsigned short u) {
    union { unsigned u; float f; } c; c.u = ((unsigned)u) << 16;
    return c.f;
}
__device__ __forceinline__ void gload_lds16(const void* g, void* l) {
    __builtin_amdgcn_global_load_lds(
        (const __attribute__((address_space(1))) unsigned int*)g,
        (__attribute__((address_space(3))) unsigned int*)l, 16, 0, 0);
}

// ---------------- copy embeddings into out[:, 0:128], xb (bf16), xf8 (fp8) ----------------
__global__ void copy_emb_kernel(const float* __restrict__ emb, float* __restrict__ out,
                                unsigned short* __restrict__ xb,
                                unsigned int* __restrict__ xf8w, int n) {
    int idx = blockIdx.x * blockDim.x + threadIdx.x;
    int total = n * 32;
    if (idx >= total) return;
    int r = idx >> 5, c4 = idx & 31;
    const float4 v = *reinterpret_cast<const float4*>(emb + (size_t)r * ND + c4 * 4);
    *reinterpret_cast<float4*>(out + (size_t)r * LDO + c4 * 4) = v;
    ushort4 b;
    b.x = (unsigned short)f2bf(v.x); b.y = (unsigned short)f2bf(v.y);
    b.z = (unsigned short)f2bf(v.z); b.w = (unsigned short)f2bf(v.w);
    *reinterpret_cast<ushort4*>(xb + (size_t)r * ND + c4 * 4) = b;
    unsigned int u = __builtin_amdgcn_cvt_pk_fp8_f32(v.x, v.y, 0, false);
    u = __builtin_amdgcn_cvt_pk_fp8_f32(v.z, v.w, u, true);
    xf8w[(size_t)r * 32 + c4] = u;
}

// ---------------- pass A: per-chunk bucket histogram (LDS only) ----------------
__global__ __launch_bounds__(256) void bucket_hist_kernel(const int* __restrict__ erow,
                                                          int* __restrict__ gcnt,
                                                          int n_edges, int nb, int ch) {
    __shared__ int cnt[256];
    int b = blockIdx.x;
    cnt[threadIdx.x] = 0;
    __syncthreads();
    int s = b * ch, e = min(n_edges, s + ch);
    for (int j = s + threadIdx.x; j < e; j += 256) {
        atomicAdd(&cnt[erow[j] >> 9], 1);
    }
    __syncthreads();
    for (int i = threadIdx.x; i < nb; i += 256) gcnt[i * NCHUNK + b] = cnt[i];
}

// ---------------- scans ----------------
__global__ __launch_bounds__(SCAN_B) void scanA_kernel(const int* __restrict__ in,
                                                       int* __restrict__ outp,
                                                       int* __restrict__ partials, int n) {
    __shared__ int sm[SCAN_B];
    int i = blockIdx.x * SCAN_B + threadIdx.x;
    int v = (i < n) ? in[i] : 0;
    sm[threadIdx.x] = v;
    __syncthreads();
#pragma unroll
    for (int off = 1; off < SCAN_B; off <<= 1) {
        int t = (threadIdx.x >= off) ? sm[threadIdx.x - off] : 0;
        __syncthreads();
        sm[threadIdx.x] += t;
        __syncthreads();
    }
    if (i < n) outp[i] = sm[threadIdx.x] - v;
    if (threadIdx.x == SCAN_B - 1) partials[blockIdx.x] = sm[SCAN_B - 1];
}

__global__ __launch_bounds__(512) void scanB_kernel(int* __restrict__ partials, int nb) {
    __shared__ int sm[512];
    int v = (threadIdx.x < nb) ? partials[threadIdx.x] : 0;
    sm[threadIdx.x] = v;
    __syncthreads();
#pragma unroll
    for (int off = 1; off < 512; off <<= 1) {
        int t = (threadIdx.x >= off) ? sm[threadIdx.x - off] : 0;
        __syncthreads();
        sm[threadIdx.x] += t;
        __syncthreads();
    }
    if (threadIdx.x < nb) partials[threadIdx.x] = sm[threadIdx.x] - v;
}

// ---------------- pass B: scatter into bucket-grouped tmp ----------------
// global base for (bucket i, chunk b) = gscan[i*NCHUNK+b] + part[i]   (NCHUNK==SCAN_B)
__global__ __launch_bounds__(256) void bucket_scatter_kernel(const int* __restrict__ erow,
                                                             const int* __restrict__ ecol,
                                                             const float* __restrict__ eval,
                                                             const int* __restrict__ gscan,
                                                             const int* __restrict__ part,
                                                             int2* __restrict__ tmp,
                                                             int n_edges, int nb, int ch) {
    __shared__ int cur[256];
    int b = blockIdx.x;
    for (int i = threadIdx.x; i < nb; i += 256)
        cur[i] = gscan[i * NCHUNK + b] + part[i];
    __syncthreads();
    int s = b * ch, e = min(n_edges, s + ch);
    for (int j = s + threadIdx.x; j < e; j += 256) {
        int r = erow[j];
        int pos = atomicAdd(&cur[r >> 9], 1);
        int2 p;
        p.x = ecol[j] | ((r & (RPB - 1)) << 17);     // col (17b) | row-low (9b)
        p.y = __float_as_int(eval[j]);
        tmp[pos] = p;
    }
}

// ---------------- pass C: per-bucket counting sort into final CSR pv + row_start ----------
__global__ __launch_bounds__(256) void bucket_sort_kernel(const int2* __restrict__ tmp,
                                                          const int* __restrict__ gscan,
                                                          const int* __restrict__ part,
                                                          int2* __restrict__ pv,
                                                          int* __restrict__ row_start,
                                                          int n, int n_edges, int nb) {
    __shared__ int hist[RPB];
    __shared__ int cur[RPB];
    __shared__ int sc[256];
    const int t = threadIdx.x;
    const int bkt = blockIdx.x;
    const int r0 = bkt << 9;
    const int s = gscan[bkt * NCHUNK] + part[bkt];
    const int e = (bkt + 1 < nb) ? (gscan[(bkt + 1) * NCHUNK] + part[bkt + 1]) : n_edges;

    for (int i = t; i < RPB; i += 256) hist[i] = 0;
    __syncthreads();
    for (int j = s + t; j < e; j += 256) atomicAdd(&hist[tmp[j].x >> 17], 1);
    __syncthreads();
    int a0 = hist[2 * t], a1 = hist[2 * t + 1];
    sc[t] = a0 + a1;
    __syncthreads();
#pragma unroll
    for (int off = 1; off < 256; off <<= 1) {
        int v = (t >= off) ? sc[t - off] : 0;
        __syncthreads();
        sc[t] += v;
        __syncthreads();
    }
    int base = s + sc[t] - a0 - a1;
    cur[2 * t] = base;
    cur[2 * t + 1] = base + a0;
    __syncthreads();
    int r1 = min(n, r0 + RPB);
    for (int i = t; i < r1 - r0; i += 256) row_start[r0 + i] = cur[i];
    if (t == 0 && r1 == n) row_start[n] = n_edges;
    __syncthreads();
    for (int j = s + t; j < e; j += 256) {
        int2 p = tmp[j];
        int pos = atomicAdd(&cur[p.x >> 17], 1);
        int2 q;
        q.x = p.x & 0x1FFFF;
        q.y = p.y;
        pv[pos] = q;
    }
}

// ---------------- SPMM (fp8 gather, unroll-4) + prop/xm formation -> pre-swizzled Axm ----
// 16 lanes per row (uint2 = 8 fp8 per lane), 16 rows per 256-thread block.
__global__ __launch_bounds__(256) void spmm_axm_kernel(const int* __restrict__ row_start,
                                                       const int2* __restrict__ pv,
                                                       const unsigned char* __restrict__ xf8,
                                                       const unsigned short* __restrict__ xb,
                                                       unsigned short* __restrict__ Axm, int n) {
    int r = blockIdx.x * 16 + (threadIdx.x >> 4);
    if (r >= n) return;
    int l = threadIdx.x & 15;        // lane within row; elems l*8 .. l*8+7
    int s = row_start[r], e = row_start[r + 1];
    float a[8] = {0.f, 0.f, 0.f, 0.f, 0.f, 0.f, 0.f, 0.f};
    int j = s;
    for (; j + 3 < e; j += 4) {
        int2 p0 = pv[j], p1 = pv[j + 1], p2 = pv[j + 2], p3 = pv[j + 3];
        uint2 q0 = *reinterpret_cast<const uint2*>(xf8 + (size_t)p0.x * ND + l * 8);
        uint2 q1 = *reinterpret_cast<const uint2*>(xf8 + (size_t)p1.x * ND + l * 8);
        uint2 q2 = *reinterpret_cast<const uint2*>(xf8 + (size_t)p2.x * ND + l * 8);
        uint2 q3 = *reinterpret_cast<const uint2*>(xf8 + (size_t)p3.x * ND + l * 8);
        float v0 = __int_as_float(p0.y), v1 = __int_as_float(p1.y);
        float v2 = __int_as_float(p2.y), v3 = __int_as_float(p3.y);
        f32x2 g0 = __builtin_amdgcn_cvt_pk_f32_fp8(q0.x, false);
        f32x2 g1 = __builtin_amdgcn_cvt_pk_f32_fp8(q0.x, true);
        f32x2 g2 = __builtin_amdgcn_cvt_pk_f32_fp8(q0.y, false);
        f32x2 g3 = __builtin_amdgcn_cvt_pk_f32_fp8(q0.y, true);
        a[0] += v0 * g0.x; a[1] += v0 * g0.y; a[2] += v0 * g1.x; a[3] += v0 * g1.y;
        a[4] += v0 * g2.x; a[5] += v0 * g2.y; a[6] += v0 * g3.x; a[7] += v0 * g3.y;
        g0 = __builtin_amdgcn_cvt_pk_f32_fp8(q1.x, false);
        g1 = __builtin_amdgcn_cvt_pk_f32_fp8(q1.x, true);
        g2 = __builtin_amdgcn_cvt_pk_f32_fp8(q1.y, false);
        g3 = __builtin_amdgcn_cvt_pk_f32_fp8(q1.y, true);
        a[0] += v1 * g0.x; a[1] += v1 * g0.y; a[2] += v1 * g1.x; a[3] += v1 * g1.y;
        a[4] += v1 * g2.x; a[5] += v1 * g2.y; a[6] += v1 * g3.x; a[7] += v1 * g3.y;
        g0 = __builtin_amdgcn_cvt_pk_f32_fp8(q2.x, false);
        g1 = __builtin_amdgcn_cvt_pk_f32_fp8(q2.x, true);
        g2 = __builtin_amdgcn_cvt_pk_f32_fp8(q2.y, false);
        g3 = __builtin_amdgcn_cvt_pk_f32_fp8(q2.y, true);
        a[0] += v2 * g0.x; a[1] += v2 * g0.y; a[2] += v2 * g1.x; a[3] += v2 * g1.y;
        a[4] += v2 * g2.x; a[5] += v2 * g2.y; a[6] += v2 * g3.x; a[7] += v2 * g3.y;
        g0 = __builtin_amdgcn_cvt_pk_f32_fp8(q3.x, false);
        g1 = __builtin_amdgcn_cvt_pk_f32_fp8(q3.x, true);
        g2 = __builtin_amdgcn_cvt_pk_f32_fp8(q3.y, false);
        g3 = __builtin_amdgcn_cvt_pk_f32_fp8(q3.y, true);
        a[0] += v3 * g0.x; a[1] += v3 * g0.y; a[2] += v3 * g1.x; a[3] += v3 * g1.y;
        a[4] += v3 * g2.x; a[5] += v3 * g2.y; a[6] += v3 * g3.x; a[7] += v3 * g3.y;
    }
    for (; j < e; ++j) {
        int2 p0 = pv[j];
        float v0 = __int_as_float(p0.y);
        uint2 q0 = *reinterpret_cast<const uint2*>(xf8 + (size_t)p0.x * ND + l * 8);
        f32x2 g0 = __builtin_amdgcn_cvt_pk_f32_fp8(q0.x, false);
        f32x2 g1 = __builtin_amdgcn_cvt_pk_f32_fp8(q0.x, true);
        f32x2 g2 = __builtin_amdgcn_cvt_pk_f32_fp8(q0.y, false);
        f32x2 g3 = __builtin_amdgcn_cvt_pk_f32_fp8(q0.y, true);
        a[0] += v0 * g0.x; a[1] += v0 * g0.y;
        a[2] += v0 * g1.x; a[3] += v0 * g1.y;
        a[4] += v0 * g2.x; a[5] += v0 * g2.y;
        a[6] += v0 * g3.x; a[7] += v0 * g3.y;
    }
    // own x row (streaming, bf16 precision)
    short8 xv = *reinterpret_cast<const short8*>(xb + (size_t)r * ND + l * 8);
    short8 prv, xmv;
#pragma unroll
    for (int q = 0; q < 8; ++q) {
        float xf = bf2f((unsigned short)xv[q]);
        prv[q] = f2bf(xf + a[q]);
        xmv[q] = f2bf(xf * a[q]);
    }
    int sz = r & 7;
    unsigned short* rowp = Axm + (size_t)r * 256;
    *reinterpret_cast<short8*>(rowp + ((l        ^ sz) << 3)) = prv;
    *reinterpret_cast<short8*>(rowp + (((16 + l) ^ sz) << 3)) = xmv;
}

// ---------------- prep: Wt2[layer][h][nr][..] pre-swizzled bf16, bsum = bgc+bbi ----------
__global__ void prep_w_kernel(const float* __restrict__ Wgc, const float* __restrict__ bgc,
                              const float* __restrict__ Wbi, const float* __restrict__ bbi,
                              short* __restrict__ Wt2, float* __restrict__ bsum) {
    int z = blockIdx.x;
    int k = blockIdx.y;            // K index within half, 0..127
    int t = threadIdx.x;
    int nn = t & 127;              // N index
    int h  = (t < 128) ? 0 : 1;    // half 0 = Wgc (prop), 1 = Wbi (xm)
    const float* src = h ? (Wbi + ((size_t)z * 128 + k) * 128)
                         : (Wgc + ((size_t)z * 128 + k) * 128);
    float v = src[nn];
    int idx16 = k >> 3, e8 = k & 7;
    size_t addr = ((size_t)(z * 2 + h) * 128 + nn) * 128 + ((idx16 ^ (nn & 7)) << 3) + e8;
    Wt2[addr] = f2bf(v);
    if (k == 0 && t < 128) bsum[z * 128 + t] = bgc[z * 128 + t] + bbi[z * 128 + t];
}

// ---------------- fused layer via MFMA (pure-copy staging) ----------------
__global__ __launch_bounds__(256) void fused_layer_mfma(
        const unsigned short* __restrict__ Axm,   // [(n+pad)][256] pre-swizzled
        const short* __restrict__ Wt2,            // [2][128][128] pre-swizzled (layer base)
        const float* __restrict__ bsum,           // [128]
        float* __restrict__ xout,                 // row stride LDO (fp32 out slice)
        unsigned short* __restrict__ xbout,       // [n][128] bf16 shadow (next x)
        unsigned char* __restrict__ xf8out,       // [n][128] fp8 shadow (next x)
        int n) {
    __shared__ short A_lds[64 * 256];    // 32 KB
    __shared__ short W_lds[128 * 128];   // 32 KB

    const int tid  = threadIdx.x;
    const int row0 = blockIdx.x * 64;
    const int lane = tid & 63;
    const int w    = tid >> 6;
    const int lrow = lane & 15;
    const int kgrp = lane >> 4;

    // ---- async stage: A tile (32KB) + W half 0 (32KB), both LDS-linear copies ----
    {
        const char* gA = (const char*)(Axm + (size_t)row0 * 256) + w * 8192 + lane * 16;
        char*       lA = (char*)A_lds + w * 8192;
        const char* gW = (const char*)Wt2 + w * 8192 + lane * 16;
        char*       lW = (char*)W_lds + w * 8192;
#pragma unroll
        for (int it = 0; it < 8; ++it) {
            gload_lds16(gA + it * 1024, lA + it * 1024);
            gload_lds16(gW + it * 1024, lW + it * 1024);
        }
    }
    asm volatile("s_waitcnt vmcnt(0)" ::: "memory");
    __syncthreads();

    f32x4 acc[8];
#pragma unroll
    for (int nf = 0; nf < 8; ++nf) acc[nf] = (f32x4){0.f, 0.f, 0.f, 0.f};

    const int ar  = w * 16 + lrow;
    const int as_ = ar & 7;

    // ---- half 0 (prop @ Wgc) ----
#pragma unroll
    for (int ksl = 0; ksl < 4; ++ksl) {
        int kkl = ksl * 4 + kgrp;                    // 0..15
        short8 af = *reinterpret_cast<const short8*>(&A_lds[ar * 256 + ((kkl ^ as_) << 3)]);
#pragma unroll
        for (int nf = 0; nf < 8; ++nf) {
            int nr = nf * 16 + lrow;
            short8 bfr = *reinterpret_cast<const short8*>(&W_lds[nr * 128 + ((kkl ^ (nr & 7)) << 3)]);
            acc[nf] = __builtin_amdgcn_mfma_f32_16x16x32_bf16(af, bfr, acc[nf], 0, 0, 0);
        }
    }
    __syncthreads();
    // ---- stage W half 1 ----
    {
        const char* gW = (const char*)Wt2 + 32768 + w * 8192 + lane * 16;
        char*       lW = (char*)W_lds + w * 8192;
#pragma unroll
        for (int it = 0; it < 8; ++it) gload_lds16(gW + it * 1024, lW + it * 1024);
    }
    asm volatile("s_waitcnt vmcnt(0)" ::: "memory");
    __syncthreads();

    // ---- half 1 (xm @ Wbi) ----
#pragma unroll
    for (int ksl = 0; ksl < 4; ++ksl) {
        int kkl = ksl * 4 + kgrp;
        short8 af = *reinterpret_cast<const short8*>(&A_lds[ar * 256 + (((16 + kkl) ^ as_) << 3)]);
#pragma unroll
        for (int nf = 0; nf < 8; ++nf) {
            int nr = nf * 16 + lrow;
            short8 bfr = *reinterpret_cast<const short8*>(&W_lds[nr * 128 + ((kkl ^ (nr & 7)) << 3)]);
            acc[nf] = __builtin_amdgcn_mfma_f32_16x16x32_bf16(af, bfr, acc[nf], 0, 0, 0);
        }
    }

    // ---- epilogue: bias + leaky + row l2-norm; out via nontemporal, bf16 + fp8 shadows ----
    float bsv[8];
#pragma unroll
    for (int nf = 0; nf < 8; ++nf) bsv[nf] = bsum[nf * 16 + lrow];

#pragma unroll
    for (int reg = 0; reg < 4; ++reg) {
        int grow = row0 + w * 16 + kgrp * 4 + reg;
        float v[8];
        float ssq = 0.f;
#pragma unroll
        for (int nf = 0; nf < 8; ++nf) {
            float tv = acc[nf][reg] + bsv[nf];
            tv = tv > 0.f ? tv : ALPHA * tv;
            v[nf] = tv;
            ssq += tv * tv;
        }
        ssq += __shfl_xor(ssq, 1);
        ssq += __shfl_xor(ssq, 2);
        ssq += __shfl_xor(ssq, 4);
        ssq += __shfl_xor(ssq, 8);
        float sc = 1.0f / sqrtf(fmaxf(ssq, L2EPS));
        if (grow < n) {
            float* op = xout + (size_t)grow * LDO;
            unsigned short* bp = xbout + (size_t)grow * ND;
            unsigned char* fp = xf8out + (size_t)grow * ND;
#pragma unroll
            for (int nf = 0; nf < 8; ++nf) {
                float ov = v[nf] * sc;
                __builtin_nontemporal_store(ov, op + nf * 16 + lrow);   // out never re-read
                bp[nf * 16 + lrow] = (unsigned short)f2bf(ov);
                unsigned int u8 = __builtin_amdgcn_cvt_pk_fp8_f32(ov, ov, 0, false);
                fp[nf * 16 + lrow] = (unsigned char)(u8 & 0xff);
            }
        }
    }
}

extern "C" void kernel_launch(void* const* d_in, const int* in_sizes, int n_in,
                              void* d_out, int out_size, void* d_ws, size_t ws_size,
                              hipStream_t stream) {
    const float* emb  = (const float*)d_in[0];
    const int*   erow = (const int*)d_in[1];
    const int*   ecol = (const int*)d_in[2];
    const float* eval = (const float*)d_in[3];
    const float* Wgc  = (const float*)d_in[4];
    const float* bgc  = (const float*)d_in[5];
    const float* Wbi  = (const float*)d_in[6];
    const float* bbi  = (const float*)d_in[7];
    float* out = (float*)d_out;

    const int n        = in_sizes[0] / ND;      // 100000
    const int n_edges  = in_sizes[1];           // 1600000
    const int n_layers = in_sizes[5] / ND;      // 3

    const int nb = (n + RPB - 1) >> 9;          // 196 buckets
    const int ch = (n_edges + NCHUNK - 1) / NCHUNK;
    const int ng = nb * NCHUNK;

    // ---- workspace layout (256B-aligned) ----
    char* ws = (char*)d_ws;
    size_t off = 0;
    auto alloc = [&](size_t bytes) { void* p = ws + off; off = (off + bytes + 255) & ~(size_t)255; return p; };
    unsigned short* xb  = (unsigned short*)alloc((size_t)n * ND * sizeof(short));        // 25.6 MB
    unsigned char*  xf8 = (unsigned char*) alloc((size_t)n * ND);                        // 12.8 MB
    unsigned short* Axm = (unsigned short*)alloc((size_t)(n + 64) * 256 * sizeof(short)); // 51.2 MB (+pad)
    int2*  pv        = (int2*) alloc((size_t)n_edges * sizeof(int2));                    // 12.8 MB
    int2*  tmp       = (int2*) alloc((size_t)n_edges * sizeof(int2));                    // 12.8 MB
    int*   row_start = (int*)  alloc((size_t)(n + 1) * sizeof(int));
    int*   gcnt      = (int*)  alloc((size_t)ng * sizeof(int));
    int*   gscan     = (int*)  alloc((size_t)ng * sizeof(int));
    int*   partials  = (int*)  alloc(512 * sizeof(int));
    short* Wt2       = (short*)alloc((size_t)n_layers * 2 * 128 * 128 * sizeof(short));
    float* bsum      = (float*)alloc((size_t)n_layers * 128 * sizeof(float));
    (void)ws_size;

    // ---- x0 -> out[:, 0:128] + xb + xf8 ----
    {
        int total = n * 32;
        copy_emb_kernel<<<(total + 255) / 256, 256, 0, stream>>>(emb, out, xb,
                                                                 (unsigned int*)xf8, n);
    }

    // ---- weight prep ----
    {
        dim3 g(n_layers, 128);
        prep_w_kernel<<<g, 256, 0, stream>>>(Wgc, bgc, Wbi, bbi, Wt2, bsum);
    }

    // ---- CSR build ----
    bucket_hist_kernel<<<NCHUNK, 256, 0, stream>>>(erow, gcnt, n_edges, nb, ch);
    {
        int nblk = (ng + SCAN_B - 1) / SCAN_B;     // 196
        scanA_kernel<<<nblk, SCAN_B, 0, stream>>>(gcnt, gscan, partials, ng);
        scanB_kernel<<<1, 512, 0, stream>>>(partials, nblk);
    }
    bucket_scatter_kernel<<<NCHUNK, 256, 0, stream>>>(erow, ecol, eval, gscan, partials,
                                                      tmp, n_edges, nb, ch);
    bucket_sort_kernel<<<nb, 256, 0, stream>>>(tmp, gscan, partials, pv, row_start,
                                               n, n_edges, nb);

    // ---- layers ----
    for (int i = 0; i < n_layers; ++i) {
        spmm_axm_kernel<<<(n + 15) / 16, 256, 0, stream>>>(row_start, pv, xf8, xb, Axm, n);
        fused_layer_mfma<<<(n + 63) / 64, 256, 0, stream>>>(
            Axm, Wt2 + (size_t)i * 2 * 128 * 128, bsum + (size_t)i * 128,
            out + (size_t)(i + 1) * ND, xb, xf8, n);
    }
}